// Round 7
// baseline (779.513 us; speedup 1.0000x reference)
//
#include <hip/hip_runtime.h>

#define N_ATOMS   100000
#define N_BONDS   220000
#define N_MESS    20000
#define N_MSG     (N_MESS + N_BONDS)        // 240000
#define ATOM_FDIM 35
#define BOND_FDIM 5
#define BOND_IN   (ATOM_FDIM + BOND_FDIM)   // 40
#define H         128
#define MAX_NB    10
#define DEPTH     6
#define KO        (ATOM_FDIM + H)           // 163
#define KC        192                       // padded K for both GEMMs

typedef __attribute__((ext_vector_type(8))) short short8;   // 8 bf16 (4 VGPRs)
typedef __attribute__((ext_vector_type(4))) float f32x4;    // MFMA C/D frag

static __device__ __forceinline__ float asf(unsigned int u) {
    union { unsigned int i; float f; } v; v.i = u; return v.f;
}
// low/high bf16 of a packed dword -> fp32
static __device__ __forceinline__ float bflo(unsigned int v) { return asf(v << 16); }
static __device__ __forceinline__ float bfhi(unsigned int v) { return asf(v & 0xffff0000u); }

static __device__ __forceinline__ unsigned short f2bf(float f) {
    union { float f; unsigned int i; } v; v.f = f;
    unsigned int x = v.i;
    return (unsigned short)((x + 0x7FFFu + ((x >> 16) & 1u)) >> 16);
}

// ---------------------------------------------------------------------------
// tree_conv: fp32 tree messages -> bf16 into BOTH msg buffers' prefix.
// ---------------------------------------------------------------------------
__global__ __launch_bounds__(256) void tree_conv(
    const float* __restrict__ tree, ushort* __restrict__ a, ushort* __restrict__ b)
{
    int i = blockIdx.x * 256 + threadIdx.x;      // grid exact
    unsigned short v = f2bf(tree[i]);
    a[i] = v; b[i] = v;
}

// ---------------------------------------------------------------------------
// fb_prep: fbonds fp32 -> bf16, same [bond][k] order (5 cells of 8 per bond).
// ---------------------------------------------------------------------------
__global__ __launch_bounds__(256) void fb_prep(
    const float* __restrict__ fbonds, ushort* __restrict__ fbc)
{
    int i = blockIdx.x * 256 + threadIdx.x;      // grid = 220000*40/256 = 34375
    fbc[i] = f2bf(fbonds[i]);
}

// ---------------------------------------------------------------------------
// wcomb_prep: WcombT[n][k] = bf16 of (k<40 ? Wi[k][n] : k<168 ? Wh[k-40][n] : 0)
// ---------------------------------------------------------------------------
__global__ __launch_bounds__(256) void wcomb_prep(
    const float* __restrict__ Wi, const float* __restrict__ Wh,
    ushort* __restrict__ WT)
{
    int i = blockIdx.x * 256 + threadIdx.x;      // grid = 128*192/256 = 96
    int n = i / KC, k = i - n * KC;
    float v = (k < BOND_IN) ? Wi[k * H + n]
            : (k < BOND_IN + H) ? Wh[(k - BOND_IN) * H + n] : 0.f;
    WT[i] = f2bf(v);
}

// ---------------------------------------------------------------------------
// wo_prep: K-reordered transposed W_o. X layout = [nei(128)|fatoms(35)|0(29)]:
//   WoT[n][k] = k<128 ? Wo[(35+k)][n] : k<163 ? Wo[k-128][n] : 0
// ---------------------------------------------------------------------------
__global__ __launch_bounds__(256) void wo_prep(
    const float* __restrict__ Wo, ushort* __restrict__ WoT)
{
    int i = blockIdx.x * 256 + threadIdx.x;      // grid = 96
    int n = i / KC, k = i - n * KC;
    float v = (k < H) ? Wo[(ATOM_FDIM + k) * H + n]
            : (k < KO) ? Wo[(k - H) * H + n] : 0.f;
    WoT[i] = f2bf(v);
}

// ---------------------------------------------------------------------------
// binput0 (MFMA): graph0 = relu(fbonds @ W_i) -> bf16. K cut to 64.
// Staging from pre-converted bf16 fbc: 160 pure 16-B copies.
// ---------------------------------------------------------------------------
__global__ __launch_bounds__(256, 4) void binput0(
    const ushort* __restrict__ fbc, const ushort* __restrict__ WT,
    ushort* __restrict__ gout)
{
    __shared__ ushort Xlds[32 * 25 * 8];

    int tid = threadIdx.x;
    int bond0 = blockIdx.x * 32;           // grid = 6875, exact
    int lane = tid & 63, wv = tid >> 6;

    if (tid < 160) {                       // b = tid/5, k8 = tid%5
        int b = tid / 5, k8 = tid - b * 5;
        *(short8*)&Xlds[(b * 25 + k8) * 8] =
            *(const short8*)&fbc[(size_t)bond0 * BOND_IN + tid * 8];
    }
    if (tid < 96) {                        // zero k in [40,64): cells 5..7
        int b = tid / 3, k8 = 5 + (tid - b * 3);
        *(float4*)&Xlds[(b * 25 + k8) * 8] = float4{0.f, 0.f, 0.f, 0.f};
    }
    __syncthreads();

    int n0 = wv * 32;
    int m_lane = lane & 15, quad = lane >> 4;
    f32x4 c00 = {0,0,0,0}, c01 = {0,0,0,0}, c10 = {0,0,0,0}, c11 = {0,0,0,0};

    #pragma unroll
    for (int s = 0; s < 2; s++) {          // K = 64 covers fb (k<40) + zeros
        short8 a0 = *(const short8*)&Xlds[((m_lane)      * 25 + s * 4 + quad) * 8];
        short8 a1 = *(const short8*)&Xlds[((16 + m_lane) * 25 + s * 4 + quad) * 8];
        short8 b0 = *(const short8*)&WT[(size_t)(n0 + m_lane)      * KC + s * 32 + quad * 8];
        short8 b1 = *(const short8*)&WT[(size_t)(n0 + 16 + m_lane) * KC + s * 32 + quad * 8];
        c00 = __builtin_amdgcn_mfma_f32_16x16x32_bf16(a0, b0, c00, 0, 0, 0);
        c01 = __builtin_amdgcn_mfma_f32_16x16x32_bf16(a0, b1, c01, 0, 0, 0);
        c10 = __builtin_amdgcn_mfma_f32_16x16x32_bf16(a1, b0, c10, 0, 0, 0);
        c11 = __builtin_amdgcn_mfma_f32_16x16x32_bf16(a1, b1, c11, 0, 0, 0);
    }

    #pragma unroll
    for (int r = 0; r < 4; r++) {
        int row0 = bond0 + quad * 4 + r;
        int row1 = row0 + 16;
        gout[(size_t)row0 * H + n0 + m_lane]      = f2bf(fmaxf(c00[r], 0.f));
        gout[(size_t)row0 * H + n0 + 16 + m_lane] = f2bf(fmaxf(c01[r], 0.f));
        gout[(size_t)row1 * H + n0 + m_lane]      = f2bf(fmaxf(c10[r], 0.f));
        gout[(size_t)row1 * H + n0 + 16 + m_lane] = f2bf(fmaxf(c11[r], 0.f));
    }
}

// ---------------------------------------------------------------------------
// mp_round (MFMA): graph_out[b] = relu([fb[b]|nei[b]|0] @ [Wi;Wh;0])
// Gather: dwordx2 per lane, 2 rows per instruction (lanes 0-31 row b,
// lanes 32-63 row b+4), pair-loop unrolled 2x -> 20 loads in flight.
// ---------------------------------------------------------------------------
__global__ __launch_bounds__(256, 4) void mp_round(
    const ushort* __restrict__ msg_in, const ushort* __restrict__ fbc,
    const int* __restrict__ bgraph, const ushort* __restrict__ WT,
    ushort* __restrict__ graph_out)
{
    __shared__ ushort Xlds[32 * 25 * 8];   // 800 cells x 16 B = 12800 B

    int tid = threadIdx.x;
    int bond0 = blockIdx.x * 32;           // grid = 6875, exact
    int lane = tid & 63, wv = tid >> 6;
    int half = lane >> 5, c = lane & 31;

    // stage fb tile (pre-converted bf16): 160 x 16 B copies
    if (tid < 160) {
        int b = tid / 5, k8 = tid - b * 5;
        *(short8*)&Xlds[(b * 25 + k8) * 8] =
            *(const short8*)&fbc[(size_t)bond0 * BOND_IN + tid * 8];
    }
    // zero pad k in [168,192): cells 21..23
    if (tid < 96) {
        int b = tid / 3, k8 = 21 + (tid - b * 3);
        *(float4*)&Xlds[(b * 25 + k8) * 8] = float4{0.f, 0.f, 0.f, 0.f};
    }
    // gather nei: wave wv owns rows {wv+4t}; pair p covers rows wv+8p (+4 for
    // upper half-wave). Each lane sums elements [c*4, c*4+4) of its row.
    #pragma unroll 2
    for (int p = 0; p < 4; p++) {
        int b = wv + p * 8 + half * 4;
        const int* bg = bgraph + (size_t)(bond0 + b) * MAX_NB;
        float s0 = 0.f, s1 = 0.f, s2 = 0.f, s3 = 0.f;
        #pragma unroll
        for (int n = 0; n < MAX_NB; n++) {
            int idx = bg[n];
            uint2 v = *(const uint2*)(msg_in + (size_t)idx * H + c * 4);
            s0 += bflo(v.x); s1 += bfhi(v.x);
            s2 += bflo(v.y); s3 += bfhi(v.y);
        }
        uint2 pk;
        pk.x = ((unsigned int)f2bf(s1) << 16) | (unsigned int)f2bf(s0);
        pk.y = ((unsigned int)f2bf(s3) << 16) | (unsigned int)f2bf(s2);
        int k = BOND_IN + c * 4;
        *(uint2*)((char*)Xlds + b * 400 + k * 2) = pk;
    }
    __syncthreads();

    int n0 = wv * 32;
    int m_lane = lane & 15, quad = lane >> 4;
    f32x4 c00 = {0,0,0,0}, c01 = {0,0,0,0}, c10 = {0,0,0,0}, c11 = {0,0,0,0};

    #pragma unroll
    for (int s = 0; s < KC / 32; s++) {
        short8 a0 = *(const short8*)&Xlds[((m_lane)      * 25 + s * 4 + quad) * 8];
        short8 a1 = *(const short8*)&Xlds[((16 + m_lane) * 25 + s * 4 + quad) * 8];
        short8 b0 = *(const short8*)&WT[(size_t)(n0 + m_lane)      * KC + s * 32 + quad * 8];
        short8 b1 = *(const short8*)&WT[(size_t)(n0 + 16 + m_lane) * KC + s * 32 + quad * 8];
        c00 = __builtin_amdgcn_mfma_f32_16x16x32_bf16(a0, b0, c00, 0, 0, 0);
        c01 = __builtin_amdgcn_mfma_f32_16x16x32_bf16(a0, b1, c01, 0, 0, 0);
        c10 = __builtin_amdgcn_mfma_f32_16x16x32_bf16(a1, b0, c10, 0, 0, 0);
        c11 = __builtin_amdgcn_mfma_f32_16x16x32_bf16(a1, b1, c11, 0, 0, 0);
    }

    #pragma unroll
    for (int r = 0; r < 4; r++) {
        int row0 = bond0 + quad * 4 + r;
        int row1 = row0 + 16;
        graph_out[(size_t)row0 * H + n0 + m_lane]      = f2bf(fmaxf(c00[r], 0.f));
        graph_out[(size_t)row0 * H + n0 + 16 + m_lane] = f2bf(fmaxf(c01[r], 0.f));
        graph_out[(size_t)row1 * H + n0 + m_lane]      = f2bf(fmaxf(c10[r], 0.f));
        graph_out[(size_t)row1 * H + n0 + 16 + m_lane] = f2bf(fmaxf(c11[r], 0.f));
    }
}

// ---------------------------------------------------------------------------
// atom_mfma: hidden[a] = relu([nei|fatoms|0] @ WoT^T + b_o)  (fp32 out)
// Same dwordx2 paired gather as mp_round; nei occupies k in [0,128).
// ---------------------------------------------------------------------------
__global__ __launch_bounds__(256, 4) void atom_mfma(
    const float* __restrict__ fatoms, const ushort* __restrict__ msg,
    const int* __restrict__ agraph, const ushort* __restrict__ WoT,
    const float* __restrict__ bo, float* __restrict__ hidden)
{
    __shared__ ushort Xlds[32 * 25 * 8];

    int tid = threadIdx.x;
    int a0 = blockIdx.x * 32;              // grid = 3125, exact
    int lane = tid & 63, wv = tid >> 6;
    int half = lane >> 5, c = lane & 31;

    // fatoms: k in [128,163)
    for (int i = tid; i < 32 * ATOM_FDIM; i += 256) {
        int b = i / ATOM_FDIM, t = i - b * ATOM_FDIM;
        int k = H + t;
        Xlds[(b * 25 + (k >> 3)) * 8 + (k & 7)] = f2bf(fatoms[(size_t)a0 * ATOM_FDIM + i]);
    }
    // zero k in [163,168)
    if (tid < 160) {
        int b = tid / 5, k = 163 + (tid - b * 5);
        Xlds[(b * 25 + (k >> 3)) * 8 + (k & 7)] = 0;
    }
    // zero cells 21..23 (k in [168,192))
    if (tid < 96) {
        int b = tid / 3, k8 = 21 + (tid - b * 3);
        *(float4*)&Xlds[(b * 25 + k8) * 8] = float4{0.f, 0.f, 0.f, 0.f};
    }
    // gather nei: k in [0,128)
    #pragma unroll 2
    for (int p = 0; p < 4; p++) {
        int b = wv + p * 8 + half * 4;
        const int* ag = agraph + (size_t)(a0 + b) * MAX_NB;
        float s0 = 0.f, s1 = 0.f, s2 = 0.f, s3 = 0.f;
        #pragma unroll
        for (int n = 0; n < MAX_NB; n++) {
            int idx = ag[n];
            uint2 v = *(const uint2*)(msg + (size_t)idx * H + c * 4);
            s0 += bflo(v.x); s1 += bfhi(v.x);
            s2 += bflo(v.y); s3 += bfhi(v.y);
        }
        uint2 pk;
        pk.x = ((unsigned int)f2bf(s1) << 16) | (unsigned int)f2bf(s0);
        pk.y = ((unsigned int)f2bf(s3) << 16) | (unsigned int)f2bf(s2);
        *(uint2*)((char*)Xlds + b * 400 + c * 8) = pk;
    }
    __syncthreads();

    int n0 = wv * 32;
    int m_lane = lane & 15, quad = lane >> 4;
    float bias0 = bo[n0 + m_lane], bias1 = bo[n0 + 16 + m_lane];
    f32x4 c00 = {bias0, bias0, bias0, bias0};
    f32x4 c01 = {bias1, bias1, bias1, bias1};
    f32x4 c10 = {bias0, bias0, bias0, bias0};
    f32x4 c11 = {bias1, bias1, bias1, bias1};

    #pragma unroll
    for (int s = 0; s < KC / 32; s++) {
        short8 a0f = *(const short8*)&Xlds[((m_lane)      * 25 + s * 4 + quad) * 8];
        short8 a1f = *(const short8*)&Xlds[((16 + m_lane) * 25 + s * 4 + quad) * 8];
        short8 b0f = *(const short8*)&WoT[(size_t)(n0 + m_lane)      * KC + s * 32 + quad * 8];
        short8 b1f = *(const short8*)&WoT[(size_t)(n0 + 16 + m_lane) * KC + s * 32 + quad * 8];
        c00 = __builtin_amdgcn_mfma_f32_16x16x32_bf16(a0f, b0f, c00, 0, 0, 0);
        c01 = __builtin_amdgcn_mfma_f32_16x16x32_bf16(a0f, b1f, c01, 0, 0, 0);
        c10 = __builtin_amdgcn_mfma_f32_16x16x32_bf16(a1f, b0f, c10, 0, 0, 0);
        c11 = __builtin_amdgcn_mfma_f32_16x16x32_bf16(a1f, b1f, c11, 0, 0, 0);
    }

    #pragma unroll
    for (int r = 0; r < 4; r++) {
        int row0 = a0 + quad * 4 + r;
        int row1 = row0 + 16;
        hidden[(size_t)row0 * H + n0 + m_lane]      = fmaxf(c00[r], 0.f);
        hidden[(size_t)row0 * H + n0 + 16 + m_lane] = fmaxf(c01[r], 0.f);
        hidden[(size_t)row1 * H + n0 + m_lane]      = fmaxf(c10[r], 0.f);
        hidden[(size_t)row1 * H + n0 + 16 + m_lane] = fmaxf(c11[r], 0.f);
    }
}

// ---------------------------------------------------------------------------
// pool_kernel: per-molecule mean over sorted mol_ids (binary-searched range).
// ---------------------------------------------------------------------------
__global__ __launch_bounds__(128) void pool_kernel(
    const float* __restrict__ hidden, const int* __restrict__ mol_ids,
    float* __restrict__ out, int n_atoms)
{
    int m = blockIdx.x;
    int j = threadIdx.x;

    int lo = 0, hi = n_atoms;
    while (lo < hi) { int mid = (lo + hi) >> 1; if (mol_ids[mid] < m) lo = mid + 1; else hi = mid; }
    int start = lo;
    hi = n_atoms;
    while (lo < hi) { int mid = (lo + hi) >> 1; if (mol_ids[mid] < m + 1) lo = mid + 1; else hi = mid; }
    int end = lo;

    float acc = 0.f;
    for (int a = start; a < end; a++)
        acc += hidden[(size_t)a * H + j];
    out[(size_t)m * H + j] = acc / fmaxf((float)(end - start), 1.f);
}

// ---------------------------------------------------------------------------
extern "C" void kernel_launch(void* const* d_in, const int* in_sizes, int n_in,
                              void* d_out, int out_size, void* d_ws, size_t ws_size,
                              hipStream_t stream)
{
    const float* fatoms  = (const float*)d_in[0];
    const float* fbonds  = (const float*)d_in[1];
    const float* tree    = (const float*)d_in[2];
    const int*   agraph  = (const int*)d_in[3];
    const int*   bgraph  = (const int*)d_in[4];
    const int*   mol_ids = (const int*)d_in[5];
    const float* W_i = (const float*)d_in[7];
    const float* W_h = (const float*)d_in[8];
    const float* W_o = (const float*)d_in[9];
    const float* b_o = (const float*)d_in[10];
    float* out = (float*)d_out;

    // ws: msgA | msgB (bf16, 61.44 MB each) | WT | WoT (48 KB each) |
    //     fbc (bf16 fbonds, 17.6 MB). hidden (fp32) aliases msgA.
    ushort* msgA = (ushort*)d_ws;
    ushort* msgB = msgA + (size_t)N_MSG * H;
    ushort* WT   = msgB + (size_t)N_MSG * H;
    ushort* WoT  = WT + (size_t)H * KC;
    ushort* fbc  = WoT + (size_t)H * KC;
    float* hidden = (float*)d_ws;

    tree_conv<<<(N_MESS * H) / 256, 256, 0, stream>>>(tree, msgA, msgB);
    fb_prep<<<(N_BONDS * BOND_IN) / 256, 256, 0, stream>>>(fbonds, fbc);
    wcomb_prep<<<(H * KC) / 256, 256, 0, stream>>>(W_i, W_h, WT);
    wo_prep<<<(H * KC) / 256, 256, 0, stream>>>(W_o, WoT);
    binput0<<<N_BONDS / 32, 256, 0, stream>>>(fbc, WT, msgA + (size_t)N_MESS * H);

    const ushort* min_ = msgA; ushort* mout = msgB;
    for (int r = 0; r < DEPTH - 1; r++) {
        mp_round<<<N_BONDS / 32, 256, 0, stream>>>(min_, fbc, bgraph, WT,
                                                   mout + (size_t)N_MESS * H);
        const ushort* t = min_; min_ = mout; mout = (ushort*)t;
    }
    // after 5 rounds the final message table is msgB (== min_)

    atom_mfma<<<N_ATOMS / 32, 256, 0, stream>>>(fatoms, min_, agraph, WoT, b_o, hidden);

    int n_mols = out_size / H;
    pool_kernel<<<n_mols, 128, 0, stream>>>(hidden, mol_ids, out, N_ATOMS);
}

// Round 8
// 699.361 us; speedup vs baseline: 1.1146x; 1.1146x over previous
//
#include <hip/hip_runtime.h>

#define N_ATOMS   100000
#define N_BONDS   220000
#define N_MESS    20000
#define N_MSG     (N_MESS + N_BONDS)        // 240000
#define ATOM_FDIM 35
#define BOND_FDIM 5
#define BOND_IN   (ATOM_FDIM + BOND_FDIM)   // 40
#define H         128
#define MAX_NB    10
#define DEPTH     6
#define KO        (ATOM_FDIM + H)           // 163
#define KC        192                       // padded K for both GEMMs

typedef __attribute__((ext_vector_type(8))) short short8;   // 8 bf16 (4 VGPRs)
typedef __attribute__((ext_vector_type(4))) float f32x4;    // MFMA C/D frag

static __device__ __forceinline__ float asf(unsigned int u) {
    union { unsigned int i; float f; } v; v.i = u; return v.f;
}
// low/high bf16 of a packed dword -> fp32
static __device__ __forceinline__ float bflo(unsigned int v) { return asf(v << 16); }
static __device__ __forceinline__ float bfhi(unsigned int v) { return asf(v & 0xffff0000u); }

static __device__ __forceinline__ unsigned short f2bf(float f) {
    union { float f; unsigned int i; } v; v.f = f;
    unsigned int x = v.i;
    return (unsigned short)((x + 0x7FFFu + ((x >> 16) & 1u)) >> 16);
}

// ---------------------------------------------------------------------------
// tree_conv: fp32 tree messages -> bf16 into BOTH msg buffers' prefix.
// ---------------------------------------------------------------------------
__global__ __launch_bounds__(256) void tree_conv(
    const float* __restrict__ tree, ushort* __restrict__ a, ushort* __restrict__ b)
{
    int i = blockIdx.x * 256 + threadIdx.x;      // grid exact
    unsigned short v = f2bf(tree[i]);
    a[i] = v; b[i] = v;
}

// ---------------------------------------------------------------------------
// fb_prep: fbonds fp32 -> bf16, same [bond][k] order (5 cells of 8 per bond).
// ---------------------------------------------------------------------------
__global__ __launch_bounds__(256) void fb_prep(
    const float* __restrict__ fbonds, ushort* __restrict__ fbc)
{
    int i = blockIdx.x * 256 + threadIdx.x;      // grid = 220000*40/256 = 34375
    fbc[i] = f2bf(fbonds[i]);
}

// ---------------------------------------------------------------------------
// wcomb_prep: WcombT[n][k] = bf16 of (k<40 ? Wi[k][n] : k<168 ? Wh[k-40][n] : 0)
// ---------------------------------------------------------------------------
__global__ __launch_bounds__(256) void wcomb_prep(
    const float* __restrict__ Wi, const float* __restrict__ Wh,
    ushort* __restrict__ WT)
{
    int i = blockIdx.x * 256 + threadIdx.x;      // grid = 128*192/256 = 96
    int n = i / KC, k = i - n * KC;
    float v = (k < BOND_IN) ? Wi[k * H + n]
            : (k < BOND_IN + H) ? Wh[(k - BOND_IN) * H + n] : 0.f;
    WT[i] = f2bf(v);
}

// ---------------------------------------------------------------------------
// wo_prep: K-reordered transposed W_o. X layout = [nei(128)|fatoms(35)|0(29)]:
//   WoT[n][k] = k<128 ? Wo[(35+k)][n] : k<163 ? Wo[k-128][n] : 0
// ---------------------------------------------------------------------------
__global__ __launch_bounds__(256) void wo_prep(
    const float* __restrict__ Wo, ushort* __restrict__ WoT)
{
    int i = blockIdx.x * 256 + threadIdx.x;      // grid = 96
    int n = i / KC, k = i - n * KC;
    float v = (k < H) ? Wo[(ATOM_FDIM + k) * H + n]
            : (k < KO) ? Wo[(k - H) * H + n] : 0.f;
    WoT[i] = f2bf(v);
}

// ---------------------------------------------------------------------------
// binput0 (MFMA): graph0 = relu(fbonds @ W_i) -> bf16. K cut to 64.
// ---------------------------------------------------------------------------
__global__ __launch_bounds__(256, 4) void binput0(
    const ushort* __restrict__ fbc, const ushort* __restrict__ WT,
    ushort* __restrict__ gout)
{
    __shared__ ushort Xlds[32 * 25 * 8];

    int tid = threadIdx.x;
    int bond0 = blockIdx.x * 32;           // grid = 6875, exact
    int lane = tid & 63, wv = tid >> 6;

    if (tid < 160) {                       // b = tid/5, k8 = tid%5
        int b = tid / 5, k8 = tid - b * 5;
        *(short8*)&Xlds[(b * 25 + k8) * 8] =
            *(const short8*)&fbc[(size_t)bond0 * BOND_IN + tid * 8];
    }
    if (tid < 96) {                        // zero k in [40,64): cells 5..7
        int b = tid / 3, k8 = 5 + (tid - b * 3);
        *(float4*)&Xlds[(b * 25 + k8) * 8] = float4{0.f, 0.f, 0.f, 0.f};
    }
    __syncthreads();

    int n0 = wv * 32;
    int m_lane = lane & 15, quad = lane >> 4;
    f32x4 c00 = {0,0,0,0}, c01 = {0,0,0,0}, c10 = {0,0,0,0}, c11 = {0,0,0,0};

    #pragma unroll
    for (int s = 0; s < 2; s++) {          // K = 64 covers fb (k<40) + zeros
        short8 a0 = *(const short8*)&Xlds[((m_lane)      * 25 + s * 4 + quad) * 8];
        short8 a1 = *(const short8*)&Xlds[((16 + m_lane) * 25 + s * 4 + quad) * 8];
        short8 b0 = *(const short8*)&WT[(size_t)(n0 + m_lane)      * KC + s * 32 + quad * 8];
        short8 b1 = *(const short8*)&WT[(size_t)(n0 + 16 + m_lane) * KC + s * 32 + quad * 8];
        c00 = __builtin_amdgcn_mfma_f32_16x16x32_bf16(a0, b0, c00, 0, 0, 0);
        c01 = __builtin_amdgcn_mfma_f32_16x16x32_bf16(a0, b1, c01, 0, 0, 0);
        c10 = __builtin_amdgcn_mfma_f32_16x16x32_bf16(a1, b0, c10, 0, 0, 0);
        c11 = __builtin_amdgcn_mfma_f32_16x16x32_bf16(a1, b1, c11, 0, 0, 0);
    }

    #pragma unroll
    for (int r = 0; r < 4; r++) {
        int row0 = bond0 + quad * 4 + r;
        int row1 = row0 + 16;
        gout[(size_t)row0 * H + n0 + m_lane]      = f2bf(fmaxf(c00[r], 0.f));
        gout[(size_t)row0 * H + n0 + 16 + m_lane] = f2bf(fmaxf(c01[r], 0.f));
        gout[(size_t)row1 * H + n0 + m_lane]      = f2bf(fmaxf(c10[r], 0.f));
        gout[(size_t)row1 * H + n0 + 16 + m_lane] = f2bf(fmaxf(c11[r], 0.f));
    }
}

// ---------------------------------------------------------------------------
// mp_round (MFMA): graph_out[b] = relu([fb[b]|nei[b]|0] @ [Wi;Wh;0])
// Gather: 4 rows per load instruction (16 lanes x 16 B = one 256 B row);
// all 10 row-loads issued into a register array before any accumulation
// -> ~80 cache lines outstanding per wave. Per lane: 8 sums = one A-frag
// cell -> single aligned b128 LDS write.
// ---------------------------------------------------------------------------
__global__ __launch_bounds__(256, 4) void mp_round(
    const ushort* __restrict__ msg_in, const ushort* __restrict__ fbc,
    const int* __restrict__ bgraph, const ushort* __restrict__ WT,
    ushort* __restrict__ graph_out)
{
    __shared__ ushort Xlds[32 * 25 * 8];   // 800 cells x 16 B = 12800 B

    int tid = threadIdx.x;
    int bond0 = blockIdx.x * 32;           // grid = 6875, exact
    int lane = tid & 63, wv = tid >> 6;
    int q = lane >> 4, c16 = lane & 15;

    // stage fb tile (pre-converted bf16): 160 x 16 B copies
    if (tid < 160) {
        int b = tid / 5, k8 = tid - b * 5;
        *(short8*)&Xlds[(b * 25 + k8) * 8] =
            *(const short8*)&fbc[(size_t)bond0 * BOND_IN + tid * 8];
    }
    // zero pad k in [168,192): cells 21..23
    if (tid < 96) {
        int b = tid / 3, k8 = 21 + (tid - b * 3);
        *(float4*)&Xlds[(b * 25 + k8) * 8] = float4{0.f, 0.f, 0.f, 0.f};
    }
    // gather nei: wave wv covers rows wv+4t, t = g*4+q; lane sums elements
    // [c16*8, c16*8+8) of its row -> cell 5+c16.
    #pragma unroll
    for (int g = 0; g < 2; g++) {
        int b = wv + 4 * (g * 4 + q);
        const int* bg = bgraph + (size_t)(bond0 + b) * MAX_NB;
        int idx[MAX_NB];
        #pragma unroll
        for (int n = 0; n < MAX_NB; n++) idx[n] = bg[n];
        uint4 v[MAX_NB];
        #pragma unroll
        for (int n = 0; n < MAX_NB; n++)
            v[n] = *(const uint4*)(msg_in + (size_t)idx[n] * H + c16 * 8);
        float s0=0.f,s1=0.f,s2=0.f,s3=0.f,s4=0.f,s5=0.f,s6=0.f,s7=0.f;
        #pragma unroll
        for (int n = 0; n < MAX_NB; n++) {
            s0 += bflo(v[n].x); s1 += bfhi(v[n].x);
            s2 += bflo(v[n].y); s3 += bfhi(v[n].y);
            s4 += bflo(v[n].z); s5 += bfhi(v[n].z);
            s6 += bflo(v[n].w); s7 += bfhi(v[n].w);
        }
        uint4 pk;
        pk.x = ((unsigned int)f2bf(s1) << 16) | (unsigned int)f2bf(s0);
        pk.y = ((unsigned int)f2bf(s3) << 16) | (unsigned int)f2bf(s2);
        pk.z = ((unsigned int)f2bf(s5) << 16) | (unsigned int)f2bf(s4);
        pk.w = ((unsigned int)f2bf(s7) << 16) | (unsigned int)f2bf(s6);
        *(uint4*)&Xlds[(b * 25 + 5 + c16) * 8] = pk;
    }
    __syncthreads();

    int n0 = wv * 32;
    int m_lane = lane & 15, quad = lane >> 4;
    f32x4 c00 = {0,0,0,0}, c01 = {0,0,0,0}, c10 = {0,0,0,0}, c11 = {0,0,0,0};

    #pragma unroll
    for (int s = 0; s < KC / 32; s++) {
        short8 a0 = *(const short8*)&Xlds[((m_lane)      * 25 + s * 4 + quad) * 8];
        short8 a1 = *(const short8*)&Xlds[((16 + m_lane) * 25 + s * 4 + quad) * 8];
        short8 b0 = *(const short8*)&WT[(size_t)(n0 + m_lane)      * KC + s * 32 + quad * 8];
        short8 b1 = *(const short8*)&WT[(size_t)(n0 + 16 + m_lane) * KC + s * 32 + quad * 8];
        c00 = __builtin_amdgcn_mfma_f32_16x16x32_bf16(a0, b0, c00, 0, 0, 0);
        c01 = __builtin_amdgcn_mfma_f32_16x16x32_bf16(a0, b1, c01, 0, 0, 0);
        c10 = __builtin_amdgcn_mfma_f32_16x16x32_bf16(a1, b0, c10, 0, 0, 0);
        c11 = __builtin_amdgcn_mfma_f32_16x16x32_bf16(a1, b1, c11, 0, 0, 0);
    }

    #pragma unroll
    for (int r = 0; r < 4; r++) {
        int row0 = bond0 + quad * 4 + r;
        int row1 = row0 + 16;
        graph_out[(size_t)row0 * H + n0 + m_lane]      = f2bf(fmaxf(c00[r], 0.f));
        graph_out[(size_t)row0 * H + n0 + 16 + m_lane] = f2bf(fmaxf(c01[r], 0.f));
        graph_out[(size_t)row1 * H + n0 + m_lane]      = f2bf(fmaxf(c10[r], 0.f));
        graph_out[(size_t)row1 * H + n0 + 16 + m_lane] = f2bf(fmaxf(c11[r], 0.f));
    }
}

// ---------------------------------------------------------------------------
// atom_mfma: hidden[a] = relu([nei|fatoms|0] @ WoT^T + b_o)  (fp32 out)
// Same max-MLP gather as mp_round; nei occupies cells 0..15.
// ---------------------------------------------------------------------------
__global__ __launch_bounds__(256, 4) void atom_mfma(
    const float* __restrict__ fatoms, const ushort* __restrict__ msg,
    const int* __restrict__ agraph, const ushort* __restrict__ WoT,
    const float* __restrict__ bo, float* __restrict__ hidden)
{
    __shared__ ushort Xlds[32 * 25 * 8];

    int tid = threadIdx.x;
    int a0 = blockIdx.x * 32;              // grid = 3125, exact
    int lane = tid & 63, wv = tid >> 6;
    int q = lane >> 4, c16 = lane & 15;

    // fatoms: k in [128,163)
    for (int i = tid; i < 32 * ATOM_FDIM; i += 256) {
        int b = i / ATOM_FDIM, t = i - b * ATOM_FDIM;
        int k = H + t;
        Xlds[(b * 25 + (k >> 3)) * 8 + (k & 7)] = f2bf(fatoms[(size_t)a0 * ATOM_FDIM + i]);
    }
    // zero k in [163,168)
    if (tid < 160) {
        int b = tid / 5, k = 163 + (tid - b * 5);
        Xlds[(b * 25 + (k >> 3)) * 8 + (k & 7)] = 0;
    }
    // zero cells 21..23 (k in [168,192))
    if (tid < 96) {
        int b = tid / 3, k8 = 21 + (tid - b * 3);
        *(float4*)&Xlds[(b * 25 + k8) * 8] = float4{0.f, 0.f, 0.f, 0.f};
    }
    // gather nei: k in [0,128) -> cell c16
    #pragma unroll
    for (int g = 0; g < 2; g++) {
        int b = wv + 4 * (g * 4 + q);
        const int* ag = agraph + (size_t)(a0 + b) * MAX_NB;
        int idx[MAX_NB];
        #pragma unroll
        for (int n = 0; n < MAX_NB; n++) idx[n] = ag[n];
        uint4 v[MAX_NB];
        #pragma unroll
        for (int n = 0; n < MAX_NB; n++)
            v[n] = *(const uint4*)(msg + (size_t)idx[n] * H + c16 * 8);
        float s0=0.f,s1=0.f,s2=0.f,s3=0.f,s4=0.f,s5=0.f,s6=0.f,s7=0.f;
        #pragma unroll
        for (int n = 0; n < MAX_NB; n++) {
            s0 += bflo(v[n].x); s1 += bfhi(v[n].x);
            s2 += bflo(v[n].y); s3 += bfhi(v[n].y);
            s4 += bflo(v[n].z); s5 += bfhi(v[n].z);
            s6 += bflo(v[n].w); s7 += bfhi(v[n].w);
        }
        uint4 pk;
        pk.x = ((unsigned int)f2bf(s1) << 16) | (unsigned int)f2bf(s0);
        pk.y = ((unsigned int)f2bf(s3) << 16) | (unsigned int)f2bf(s2);
        pk.z = ((unsigned int)f2bf(s5) << 16) | (unsigned int)f2bf(s4);
        pk.w = ((unsigned int)f2bf(s7) << 16) | (unsigned int)f2bf(s6);
        *(uint4*)&Xlds[(b * 25 + c16) * 8] = pk;
    }
    __syncthreads();

    int n0 = wv * 32;
    int m_lane = lane & 15, quad = lane >> 4;
    float bias0 = bo[n0 + m_lane], bias1 = bo[n0 + 16 + m_lane];
    f32x4 c00 = {bias0, bias0, bias0, bias0};
    f32x4 c01 = {bias1, bias1, bias1, bias1};
    f32x4 c10 = {bias0, bias0, bias0, bias0};
    f32x4 c11 = {bias1, bias1, bias1, bias1};

    #pragma unroll
    for (int s = 0; s < KC / 32; s++) {
        short8 a0f = *(const short8*)&Xlds[((m_lane)      * 25 + s * 4 + quad) * 8];
        short8 a1f = *(const short8*)&Xlds[((16 + m_lane) * 25 + s * 4 + quad) * 8];
        short8 b0f = *(const short8*)&WoT[(size_t)(n0 + m_lane)      * KC + s * 32 + quad * 8];
        short8 b1f = *(const short8*)&WoT[(size_t)(n0 + 16 + m_lane) * KC + s * 32 + quad * 8];
        c00 = __builtin_amdgcn_mfma_f32_16x16x32_bf16(a0f, b0f, c00, 0, 0, 0);
        c01 = __builtin_amdgcn_mfma_f32_16x16x32_bf16(a0f, b1f, c01, 0, 0, 0);
        c10 = __builtin_amdgcn_mfma_f32_16x16x32_bf16(a1f, b0f, c10, 0, 0, 0);
        c11 = __builtin_amdgcn_mfma_f32_16x16x32_bf16(a1f, b1f, c11, 0, 0, 0);
    }

    #pragma unroll
    for (int r = 0; r < 4; r++) {
        int row0 = a0 + quad * 4 + r;
        int row1 = row0 + 16;
        hidden[(size_t)row0 * H + n0 + m_lane]      = fmaxf(c00[r], 0.f);
        hidden[(size_t)row0 * H + n0 + 16 + m_lane] = fmaxf(c01[r], 0.f);
        hidden[(size_t)row1 * H + n0 + m_lane]      = fmaxf(c10[r], 0.f);
        hidden[(size_t)row1 * H + n0 + 16 + m_lane] = fmaxf(c11[r], 0.f);
    }
}

// ---------------------------------------------------------------------------
// pool_kernel: per-molecule mean over sorted mol_ids (binary-searched range).
// ---------------------------------------------------------------------------
__global__ __launch_bounds__(128) void pool_kernel(
    const float* __restrict__ hidden, const int* __restrict__ mol_ids,
    float* __restrict__ out, int n_atoms)
{
    int m = blockIdx.x;
    int j = threadIdx.x;

    int lo = 0, hi = n_atoms;
    while (lo < hi) { int mid = (lo + hi) >> 1; if (mol_ids[mid] < m) lo = mid + 1; else hi = mid; }
    int start = lo;
    hi = n_atoms;
    while (lo < hi) { int mid = (lo + hi) >> 1; if (mol_ids[mid] < m + 1) lo = mid + 1; else hi = mid; }
    int end = lo;

    float acc = 0.f;
    for (int a = start; a < end; a++)
        acc += hidden[(size_t)a * H + j];
    out[(size_t)m * H + j] = acc / fmaxf((float)(end - start), 1.f);
}

// ---------------------------------------------------------------------------
extern "C" void kernel_launch(void* const* d_in, const int* in_sizes, int n_in,
                              void* d_out, int out_size, void* d_ws, size_t ws_size,
                              hipStream_t stream)
{
    const float* fatoms  = (const float*)d_in[0];
    const float* fbonds  = (const float*)d_in[1];
    const float* tree    = (const float*)d_in[2];
    const int*   agraph  = (const int*)d_in[3];
    const int*   bgraph  = (const int*)d_in[4];
    const int*   mol_ids = (const int*)d_in[5];
    const float* W_i = (const float*)d_in[7];
    const float* W_h = (const float*)d_in[8];
    const float* W_o = (const float*)d_in[9];
    const float* b_o = (const float*)d_in[10];
    float* out = (float*)d_out;

    // ws: msgA | msgB (bf16, 61.44 MB each) | WT | WoT (48 KB each) |
    //     fbc (bf16 fbonds, 17.6 MB). hidden (fp32) aliases msgA.
    ushort* msgA = (ushort*)d_ws;
    ushort* msgB = msgA + (size_t)N_MSG * H;
    ushort* WT   = msgB + (size_t)N_MSG * H;
    ushort* WoT  = WT + (size_t)H * KC;
    ushort* fbc  = WoT + (size_t)H * KC;
    float* hidden = (float*)d_ws;

    tree_conv<<<(N_MESS * H) / 256, 256, 0, stream>>>(tree, msgA, msgB);
    fb_prep<<<(N_BONDS * BOND_IN) / 256, 256, 0, stream>>>(fbonds, fbc);
    wcomb_prep<<<(H * KC) / 256, 256, 0, stream>>>(W_i, W_h, WT);
    wo_prep<<<(H * KC) / 256, 256, 0, stream>>>(W_o, WoT);
    binput0<<<N_BONDS / 32, 256, 0, stream>>>(fbc, WT, msgA + (size_t)N_MESS * H);

    const ushort* min_ = msgA; ushort* mout = msgB;
    for (int r = 0; r < DEPTH - 1; r++) {
        mp_round<<<N_BONDS / 32, 256, 0, stream>>>(min_, fbc, bgraph, WT,
                                                   mout + (size_t)N_MESS * H);
        const ushort* t = min_; min_ = mout; mout = (ushort*)t;
    }
    // after 5 rounds the final message table is msgB (== min_)

    atom_mfma<<<N_ATOMS / 32, 256, 0, stream>>>(fatoms, min_, agraph, WoT, b_o, hidden);

    int n_mols = out_size / H;
    pool_kernel<<<n_mols, 128, 0, stream>>>(hidden, mol_ids, out, N_ATOMS);
}

// Round 9
// 678.968 us; speedup vs baseline: 1.1481x; 1.0300x over previous
//
#include <hip/hip_runtime.h>

#define N_ATOMS   100000
#define N_BONDS   220000
#define N_MESS    20000
#define N_MSG     (N_MESS + N_BONDS)        // 240000
#define ATOM_FDIM 35
#define BOND_FDIM 5
#define BOND_IN   (ATOM_FDIM + BOND_FDIM)   // 40
#define H         128
#define MAX_NB    10
#define DEPTH     6
#define KO        (ATOM_FDIM + H)           // 163
#define KC        192                       // padded K for both GEMMs

typedef __attribute__((ext_vector_type(8))) short short8;   // 8 bf16 (4 VGPRs)
typedef __attribute__((ext_vector_type(4))) float f32x4;    // MFMA C/D frag

static __device__ __forceinline__ float asf(unsigned int u) {
    union { unsigned int i; float f; } v; v.i = u; return v.f;
}
static __device__ __forceinline__ float bflo(unsigned int v) { return asf(v << 16); }
static __device__ __forceinline__ float bfhi(unsigned int v) { return asf(v & 0xffff0000u); }

static __device__ __forceinline__ unsigned short f2bf(float f) {
    union { float f; unsigned int i; } v; v.f = f;
    unsigned int x = v.i;
    return (unsigned short)((x + 0x7FFFu + ((x >> 16) & 1u)) >> 16);
}

// ---------------------------------------------------------------------------
// prep: one kernel for all format conversions + out zeroing.
//   [0, T0)   tree fp32 -> bf16 into msgA & msgB prefix
//   [T0, T1)  fbonds fp32 -> bf16 (fbc)
//   [T1, T2)  WcombT[n][k] = k<40 ? Wi[k][n] : k<168 ? Wh[k-40][n] : 0
//   [T2, T3)  WoT[n][k]    = k<128 ? Wo[35+k][n] : k<163 ? Wo[k-128][n] : 0
//   [T3, T3+n_out) out = 0  (atom stage accumulates into out via atomics)
// ---------------------------------------------------------------------------
#define PT0 (N_MESS * H)                    // 2,560,000
#define PT1 (PT0 + N_BONDS * BOND_IN)       // 11,360,000
#define PT2 (PT1 + H * KC)                  // 11,384,576
#define PT3 (PT2 + H * KC)                  // 11,409,152

__global__ __launch_bounds__(256) void prep(
    const float* __restrict__ tree, const float* __restrict__ fbonds,
    const float* __restrict__ Wi, const float* __restrict__ Wh,
    const float* __restrict__ Wo,
    ushort* __restrict__ msgA, ushort* __restrict__ msgB,
    ushort* __restrict__ fbc, ushort* __restrict__ WT,
    ushort* __restrict__ WoT, float* __restrict__ out, int n_out)
{
    int i = blockIdx.x * 256 + threadIdx.x;
    if (i < PT0) {
        unsigned short v = f2bf(tree[i]);
        msgA[i] = v; msgB[i] = v;
    } else if (i < PT1) {
        int j = i - PT0;
        fbc[j] = f2bf(fbonds[j]);
    } else if (i < PT2) {
        int j = i - PT1;
        int n = j / KC, k = j - n * KC;
        float v = (k < BOND_IN) ? Wi[k * H + n]
                : (k < BOND_IN + H) ? Wh[(k - BOND_IN) * H + n] : 0.f;
        WT[j] = f2bf(v);
    } else if (i < PT3) {
        int j = i - PT2;
        int n = j / KC, k = j - n * KC;
        float v = (k < H) ? Wo[(ATOM_FDIM + k) * H + n]
                : (k < KO) ? Wo[(k - H) * H + n] : 0.f;
        WoT[j] = f2bf(v);
    } else {
        int j = i - PT3;
        if (j < n_out) out[j] = 0.f;
    }
}

// ---------------------------------------------------------------------------
// binput0 (MFMA): graph0 = relu(fbonds @ W_i) -> bf16. K cut to 64.
// ---------------------------------------------------------------------------
__global__ __launch_bounds__(256, 4) void binput0(
    const ushort* __restrict__ fbc, const ushort* __restrict__ WT,
    ushort* __restrict__ gout)
{
    __shared__ ushort Xlds[32 * 25 * 8];

    int tid = threadIdx.x;
    int bond0 = blockIdx.x * 32;           // grid = 6875, exact
    int lane = tid & 63, wv = tid >> 6;

    if (tid < 160) {                       // b = tid/5, k8 = tid%5
        int b = tid / 5, k8 = tid - b * 5;
        *(short8*)&Xlds[(b * 25 + k8) * 8] =
            *(const short8*)&fbc[(size_t)bond0 * BOND_IN + tid * 8];
    }
    if (tid < 96) {                        // zero k in [40,64): cells 5..7
        int b = tid / 3, k8 = 5 + (tid - b * 3);
        *(float4*)&Xlds[(b * 25 + k8) * 8] = float4{0.f, 0.f, 0.f, 0.f};
    }
    __syncthreads();

    int n0 = wv * 32;
    int m_lane = lane & 15, quad = lane >> 4;
    f32x4 c00 = {0,0,0,0}, c01 = {0,0,0,0}, c10 = {0,0,0,0}, c11 = {0,0,0,0};

    #pragma unroll
    for (int s = 0; s < 2; s++) {          // K = 64 covers fb (k<40) + zeros
        short8 a0 = *(const short8*)&Xlds[((m_lane)      * 25 + s * 4 + quad) * 8];
        short8 a1 = *(const short8*)&Xlds[((16 + m_lane) * 25 + s * 4 + quad) * 8];
        short8 b0 = *(const short8*)&WT[(size_t)(n0 + m_lane)      * KC + s * 32 + quad * 8];
        short8 b1 = *(const short8*)&WT[(size_t)(n0 + 16 + m_lane) * KC + s * 32 + quad * 8];
        c00 = __builtin_amdgcn_mfma_f32_16x16x32_bf16(a0, b0, c00, 0, 0, 0);
        c01 = __builtin_amdgcn_mfma_f32_16x16x32_bf16(a0, b1, c01, 0, 0, 0);
        c10 = __builtin_amdgcn_mfma_f32_16x16x32_bf16(a1, b0, c10, 0, 0, 0);
        c11 = __builtin_amdgcn_mfma_f32_16x16x32_bf16(a1, b1, c11, 0, 0, 0);
    }

    #pragma unroll
    for (int r = 0; r < 4; r++) {
        int row0 = bond0 + quad * 4 + r;
        int row1 = row0 + 16;
        gout[(size_t)row0 * H + n0 + m_lane]      = f2bf(fmaxf(c00[r], 0.f));
        gout[(size_t)row0 * H + n0 + 16 + m_lane] = f2bf(fmaxf(c01[r], 0.f));
        gout[(size_t)row1 * H + n0 + m_lane]      = f2bf(fmaxf(c10[r], 0.f));
        gout[(size_t)row1 * H + n0 + 16 + m_lane] = f2bf(fmaxf(c11[r], 0.f));
    }
}

// ---------------------------------------------------------------------------
// mp_round (MFMA): graph_out[b] = relu([fb[b]|nei[b]|0] @ [Wi;Wh;0])
// Gather via async global_load_lds (zero VGPR per outstanding load, so the
// compiler cannot re-serialize): each size-16 instruction pulls 4 rows
// (16 lanes x 16 B each, per-lane global addr; LDS dest = uniform base +
// lane*16 -> 4 rows contiguous). Wave issues 10 instrs (40 rows = 4 bonds),
// drains once, sums from LDS. Two 16-bond halves; no barrier until MFMA.
// LDS: Xlds 12800 + stage 40960 = 53760 B -> 3 blocks/CU.
// ---------------------------------------------------------------------------
__global__ __launch_bounds__(256, 3) void mp_round(
    const ushort* __restrict__ msg_in, const ushort* __restrict__ fbc,
    const int* __restrict__ bgraph, const ushort* __restrict__ WT,
    ushort* __restrict__ graph_out)
{
    __shared__ ushort Xlds[32 * 25 * 8];    // 12800 B
    __shared__ ushort stage[160 * 128];     // 160 rows x 256 B = 40960 B

    int tid = threadIdx.x;
    int bond0 = blockIdx.x * 32;            // grid = 6875, exact
    int lane = tid & 63, wv = tid >> 6;

    // stage fb tile (pre-converted bf16): 160 x 16 B copies
    if (tid < 160) {
        int b = tid / 5, k8 = tid - b * 5;
        *(short8*)&Xlds[(b * 25 + k8) * 8] =
            *(const short8*)&fbc[(size_t)bond0 * BOND_IN + tid * 8];
    }
    // zero pad k in [168,192): cells 21..23
    if (tid < 96) {
        int b = tid / 3, k8 = 21 + (tid - b * 3);
        *(float4*)&Xlds[(b * 25 + k8) * 8] = float4{0.f, 0.f, 0.f, 0.f};
    }

    // prefetch this wave's 2x40 gather indices (bonds wv*4.. +4 per half)
    int idx0 = 0, idx1 = 0;
    if (lane < 40) {
        idx0 = bgraph[(size_t)(bond0 + wv * 4) * MAX_NB + lane];
        idx1 = bgraph[(size_t)(bond0 + 16 + wv * 4) * MAX_NB + lane];
    }

    int grp = lane >> 4, c16 = lane & 15;
    ushort* stageW = &stage[wv * 40 * 128];   // this wave's 40-row region

    #pragma unroll
    for (int h = 0; h < 2; h++) {
        int hsrc = h ? idx1 : idx0;
        // issue 10 async 4-row loads (40 rows), all in flight
        #pragma unroll
        for (int i = 0; i < 10; i++) {
            int ridx = __shfl(hsrc, i * 4 + grp);
            const ushort* gp = msg_in + (size_t)ridx * H + c16 * 8;
            __builtin_amdgcn_global_load_lds(
                (const __attribute__((address_space(1))) void*)gp,
                (__attribute__((address_space(3))) void*)&stageW[(i * 4) * 128],
                16, 0, 0);
        }
        __builtin_amdgcn_s_waitcnt(0);      // drain this wave's loads
        // sum: lane group (grp = bond-local) x c16 covers 4 bonds x 128 cols
        {
            int bl = grp;
            float s0=0.f,s1=0.f,s2=0.f,s3=0.f,s4=0.f,s5=0.f,s6=0.f,s7=0.f;
            #pragma unroll
            for (int n = 0; n < MAX_NB; n++) {
                uint4 v = *(const uint4*)&stageW[(bl * 10 + n) * 128 + c16 * 8];
                s0 += bflo(v.x); s1 += bfhi(v.x);
                s2 += bflo(v.y); s3 += bfhi(v.y);
                s4 += bflo(v.z); s5 += bfhi(v.z);
                s6 += bflo(v.w); s7 += bfhi(v.w);
            }
            uint4 pk;
            pk.x = ((unsigned int)f2bf(s1) << 16) | (unsigned int)f2bf(s0);
            pk.y = ((unsigned int)f2bf(s3) << 16) | (unsigned int)f2bf(s2);
            pk.z = ((unsigned int)f2bf(s5) << 16) | (unsigned int)f2bf(s4);
            pk.w = ((unsigned int)f2bf(s7) << 16) | (unsigned int)f2bf(s6);
            int b = h * 16 + wv * 4 + bl;
            *(uint4*)&Xlds[(b * 25 + 5 + c16) * 8] = pk;
        }
    }
    __syncthreads();

    int n0 = wv * 32;
    int m_lane = lane & 15, quad = lane >> 4;
    f32x4 c00 = {0,0,0,0}, c01 = {0,0,0,0}, c10 = {0,0,0,0}, c11 = {0,0,0,0};

    #pragma unroll
    for (int s = 0; s < KC / 32; s++) {
        short8 a0 = *(const short8*)&Xlds[((m_lane)      * 25 + s * 4 + quad) * 8];
        short8 a1 = *(const short8*)&Xlds[((16 + m_lane) * 25 + s * 4 + quad) * 8];
        short8 b0 = *(const short8*)&WT[(size_t)(n0 + m_lane)      * KC + s * 32 + quad * 8];
        short8 b1 = *(const short8*)&WT[(size_t)(n0 + 16 + m_lane) * KC + s * 32 + quad * 8];
        c00 = __builtin_amdgcn_mfma_f32_16x16x32_bf16(a0, b0, c00, 0, 0, 0);
        c01 = __builtin_amdgcn_mfma_f32_16x16x32_bf16(a0, b1, c01, 0, 0, 0);
        c10 = __builtin_amdgcn_mfma_f32_16x16x32_bf16(a1, b0, c10, 0, 0, 0);
        c11 = __builtin_amdgcn_mfma_f32_16x16x32_bf16(a1, b1, c11, 0, 0, 0);
    }

    #pragma unroll
    for (int r = 0; r < 4; r++) {
        int row0 = bond0 + quad * 4 + r;
        int row1 = row0 + 16;
        graph_out[(size_t)row0 * H + n0 + m_lane]      = f2bf(fmaxf(c00[r], 0.f));
        graph_out[(size_t)row0 * H + n0 + 16 + m_lane] = f2bf(fmaxf(c01[r], 0.f));
        graph_out[(size_t)row1 * H + n0 + m_lane]      = f2bf(fmaxf(c10[r], 0.f));
        graph_out[(size_t)row1 * H + n0 + 16 + m_lane] = f2bf(fmaxf(c11[r], 0.f));
    }
}

// ---------------------------------------------------------------------------
// atom_mfma: relu([nei|fatoms|0] @ WoT^T + b_o), then per-molecule partial
// sums reduced in LDS (mol_ids sorted -> few segments per 32-atom tile) and
// atomicAdd'ed into out. No hidden buffer.
// LDS: Xlds 12800 + htile 16384 + mlds 128 = 29312 B.
// ---------------------------------------------------------------------------
__global__ __launch_bounds__(256, 4) void atom_mfma(
    const float* __restrict__ fatoms, const ushort* __restrict__ msg,
    const int* __restrict__ agraph, const ushort* __restrict__ WoT,
    const float* __restrict__ bo, const int* __restrict__ mol_ids,
    float* __restrict__ out)
{
    __shared__ ushort Xlds[32 * 25 * 8];
    __shared__ float htile[32 * H];
    __shared__ int mlds[32];

    int tid = threadIdx.x;
    int a0 = blockIdx.x * 32;              // grid = 3125, exact
    int lane = tid & 63, wv = tid >> 6;
    int q = lane >> 4, c16 = lane & 15;

    // fatoms: k in [128,163)
    for (int i = tid; i < 32 * ATOM_FDIM; i += 256) {
        int b = i / ATOM_FDIM, t = i - b * ATOM_FDIM;
        int k = H + t;
        Xlds[(b * 25 + (k >> 3)) * 8 + (k & 7)] = f2bf(fatoms[(size_t)a0 * ATOM_FDIM + i]);
    }
    // zero k in [163,168)
    if (tid < 160) {
        int b = tid / 5, k = 163 + (tid - b * 5);
        Xlds[(b * 25 + (k >> 3)) * 8 + (k & 7)] = 0;
    }
    // zero cells 21..23 (k in [168,192))
    if (tid < 96) {
        int b = tid / 3, k8 = 21 + (tid - b * 3);
        *(float4*)&Xlds[(b * 25 + k8) * 8] = float4{0.f, 0.f, 0.f, 0.f};
    }
    if (tid < 32) mlds[tid] = mol_ids[a0 + tid];
    // gather nei: k in [0,128) -> cell c16
    #pragma unroll
    for (int g = 0; g < 2; g++) {
        int b = wv + 4 * (g * 4 + q);
        const int* ag = agraph + (size_t)(a0 + b) * MAX_NB;
        int idx[MAX_NB];
        #pragma unroll
        for (int n = 0; n < MAX_NB; n++) idx[n] = ag[n];
        uint4 v[MAX_NB];
        #pragma unroll
        for (int n = 0; n < MAX_NB; n++)
            v[n] = *(const uint4*)(msg + (size_t)idx[n] * H + c16 * 8);
        float s0=0.f,s1=0.f,s2=0.f,s3=0.f,s4=0.f,s5=0.f,s6=0.f,s7=0.f;
        #pragma unroll
        for (int n = 0; n < MAX_NB; n++) {
            s0 += bflo(v[n].x); s1 += bfhi(v[n].x);
            s2 += bflo(v[n].y); s3 += bfhi(v[n].y);
            s4 += bflo(v[n].z); s5 += bfhi(v[n].z);
            s6 += bflo(v[n].w); s7 += bfhi(v[n].w);
        }
        uint4 pk;
        pk.x = ((unsigned int)f2bf(s1) << 16) | (unsigned int)f2bf(s0);
        pk.y = ((unsigned int)f2bf(s3) << 16) | (unsigned int)f2bf(s2);
        pk.z = ((unsigned int)f2bf(s5) << 16) | (unsigned int)f2bf(s4);
        pk.w = ((unsigned int)f2bf(s7) << 16) | (unsigned int)f2bf(s6);
        *(uint4*)&Xlds[(b * 25 + c16) * 8] = pk;
    }
    __syncthreads();

    int n0 = wv * 32;
    int m_lane = lane & 15, quad = lane >> 4;
    float bias0 = bo[n0 + m_lane], bias1 = bo[n0 + 16 + m_lane];
    f32x4 c00 = {bias0, bias0, bias0, bias0};
    f32x4 c01 = {bias1, bias1, bias1, bias1};
    f32x4 c10 = {bias0, bias0, bias0, bias0};
    f32x4 c11 = {bias1, bias1, bias1, bias1};

    #pragma unroll
    for (int s = 0; s < KC / 32; s++) {
        short8 a0f = *(const short8*)&Xlds[((m_lane)      * 25 + s * 4 + quad) * 8];
        short8 a1f = *(const short8*)&Xlds[((16 + m_lane) * 25 + s * 4 + quad) * 8];
        short8 b0f = *(const short8*)&WoT[(size_t)(n0 + m_lane)      * KC + s * 32 + quad * 8];
        short8 b1f = *(const short8*)&WoT[(size_t)(n0 + 16 + m_lane) * KC + s * 32 + quad * 8];
        c00 = __builtin_amdgcn_mfma_f32_16x16x32_bf16(a0f, b0f, c00, 0, 0, 0);
        c01 = __builtin_amdgcn_mfma_f32_16x16x32_bf16(a0f, b1f, c01, 0, 0, 0);
        c10 = __builtin_amdgcn_mfma_f32_16x16x32_bf16(a1f, b0f, c10, 0, 0, 0);
        c11 = __builtin_amdgcn_mfma_f32_16x16x32_bf16(a1f, b1f, c11, 0, 0, 0);
    }

    #pragma unroll
    for (int r = 0; r < 4; r++) {
        int r0 = quad * 4 + r, r1 = r0 + 16;
        htile[r0 * H + n0 + m_lane]      = fmaxf(c00[r], 0.f);
        htile[r0 * H + n0 + 16 + m_lane] = fmaxf(c01[r], 0.f);
        htile[r1 * H + n0 + m_lane]      = fmaxf(c10[r], 0.f);
        htile[r1 * H + n0 + 16 + m_lane] = fmaxf(c11[r], 0.f);
    }
    __syncthreads();

    // segmented reduce over the 32-atom tile, one atomicAdd per (segment,col)
    if (tid < H) {
        int j = tid;
        float acc = 0.f;
        int cur = mlds[0];
        for (int r = 0; r < 32; r++) {
            int m = mlds[r];
            if (m != cur) {
                atomicAdd(&out[(size_t)cur * H + j], acc);
                acc = 0.f; cur = m;
            }
            acc += htile[r * H + j];
        }
        atomicAdd(&out[(size_t)cur * H + j], acc);
    }
}

// ---------------------------------------------------------------------------
// pool_div: out[m] /= count(m)  (counts via binary search on sorted mol_ids)
// ---------------------------------------------------------------------------
__global__ __launch_bounds__(128) void pool_div(
    const int* __restrict__ mol_ids, float* __restrict__ out, int n_atoms)
{
    int m = blockIdx.x;
    int j = threadIdx.x;

    int lo = 0, hi = n_atoms;
    while (lo < hi) { int mid = (lo + hi) >> 1; if (mol_ids[mid] < m) lo = mid + 1; else hi = mid; }
    int start = lo;
    hi = n_atoms;
    while (lo < hi) { int mid = (lo + hi) >> 1; if (mol_ids[mid] < m + 1) lo = mid + 1; else hi = mid; }
    int end = lo;

    out[(size_t)m * H + j] /= fmaxf((float)(end - start), 1.f);
}

// ---------------------------------------------------------------------------
extern "C" void kernel_launch(void* const* d_in, const int* in_sizes, int n_in,
                              void* d_out, int out_size, void* d_ws, size_t ws_size,
                              hipStream_t stream)
{
    const float* fatoms  = (const float*)d_in[0];
    const float* fbonds  = (const float*)d_in[1];
    const float* tree    = (const float*)d_in[2];
    const int*   agraph  = (const int*)d_in[3];
    const int*   bgraph  = (const int*)d_in[4];
    const int*   mol_ids = (const int*)d_in[5];
    const float* W_i = (const float*)d_in[7];
    const float* W_h = (const float*)d_in[8];
    const float* W_o = (const float*)d_in[9];
    const float* b_o = (const float*)d_in[10];
    float* out = (float*)d_out;

    // ws: msgA | msgB (bf16, 61.44 MB each) | WT | WoT (48 KB each) | fbc (17.6 MB)
    ushort* msgA = (ushort*)d_ws;
    ushort* msgB = msgA + (size_t)N_MSG * H;
    ushort* WT   = msgB + (size_t)N_MSG * H;
    ushort* WoT  = WT + (size_t)H * KC;
    ushort* fbc  = WoT + (size_t)H * KC;

    int prep_total = PT3 + out_size;
    prep<<<(prep_total + 255) / 256, 256, 0, stream>>>(
        tree, fbonds, W_i, W_h, W_o, msgA, msgB, fbc, WT, WoT, out, out_size);

    binput0<<<N_BONDS / 32, 256, 0, stream>>>(fbc, WT, msgA + (size_t)N_MESS * H);

    const ushort* min_ = msgA; ushort* mout = msgB;
    for (int r = 0; r < DEPTH - 1; r++) {
        mp_round<<<N_BONDS / 32, 256, 0, stream>>>(min_, fbc, bgraph, WT,
                                                   mout + (size_t)N_MESS * H);
        const ushort* t = min_; min_ = mout; mout = (ushort*)t;
    }
    // after 5 rounds the final message table is msgB (== min_)

    atom_mfma<<<N_ATOMS / 32, 256, 0, stream>>>(fatoms, min_, agraph, WoT, b_o,
                                                mol_ids, out);

    int n_mols = out_size / H;
    pool_div<<<n_mols, 128, 0, stream>>>(mol_ids, out, N_ATOMS);
}

// Round 10
// 665.071 us; speedup vs baseline: 1.1721x; 1.0209x over previous
//
#include <hip/hip_runtime.h>

#define N_ATOMS   100000
#define N_BONDS   220000
#define N_MESS    20000
#define N_MSG     (N_MESS + N_BONDS)        // 240000
#define ATOM_FDIM 35
#define BOND_FDIM 5
#define BOND_IN   (ATOM_FDIM + BOND_FDIM)   // 40
#define H         128
#define MAX_NB    10
#define DEPTH     6
#define KO        (ATOM_FDIM + H)           // 163
#define KC        192                       // padded K for both GEMMs

typedef __attribute__((ext_vector_type(8))) short short8;   // 8 bf16 (4 VGPRs)
typedef __attribute__((ext_vector_type(4))) float f32x4;    // MFMA C/D frag

static __device__ __forceinline__ float asf(unsigned int u) {
    union { unsigned int i; float f; } v; v.i = u; return v.f;
}
static __device__ __forceinline__ float bflo(unsigned int v) { return asf(v << 16); }
static __device__ __forceinline__ float bfhi(unsigned int v) { return asf(v & 0xffff0000u); }

static __device__ __forceinline__ unsigned short f2bf(float f) {
    union { float f; unsigned int i; } v; v.f = f;
    unsigned int x = v.i;
    return (unsigned short)((x + 0x7FFFu + ((x >> 16) & 1u)) >> 16);
}

// ---------------------------------------------------------------------------
// prep: one kernel for all format conversions + out zeroing.
// ---------------------------------------------------------------------------
#define PT0 (N_MESS * H)                    // 2,560,000
#define PT1 (PT0 + N_BONDS * BOND_IN)       // 11,360,000
#define PT2 (PT1 + H * KC)                  // 11,384,576
#define PT3 (PT2 + H * KC)                  // 11,409,152

__global__ __launch_bounds__(256) void prep(
    const float* __restrict__ tree, const float* __restrict__ fbonds,
    const float* __restrict__ Wi, const float* __restrict__ Wh,
    const float* __restrict__ Wo,
    ushort* __restrict__ msgA, ushort* __restrict__ msgB,
    ushort* __restrict__ fbc, ushort* __restrict__ WT,
    ushort* __restrict__ WoT, float* __restrict__ out, int n_out)
{
    int i = blockIdx.x * 256 + threadIdx.x;
    if (i < PT0) {
        unsigned short v = f2bf(tree[i]);
        msgA[i] = v; msgB[i] = v;
    } else if (i < PT1) {
        int j = i - PT0;
        fbc[j] = f2bf(fbonds[j]);
    } else if (i < PT2) {
        int j = i - PT1;
        int n = j / KC, k = j - n * KC;
        float v = (k < BOND_IN) ? Wi[k * H + n]
                : (k < BOND_IN + H) ? Wh[(k - BOND_IN) * H + n] : 0.f;
        WT[j] = f2bf(v);
    } else if (i < PT3) {
        int j = i - PT2;
        int n = j / KC, k = j - n * KC;
        float v = (k < H) ? Wo[(ATOM_FDIM + k) * H + n]
                : (k < KO) ? Wo[(k - H) * H + n] : 0.f;
        WoT[j] = f2bf(v);
    } else {
        int j = i - PT3;
        if (j < n_out) out[j] = 0.f;
    }
}

// ---------------------------------------------------------------------------
// binput0 (MFMA): graph0 = relu(fbonds @ W_i) -> bf16. K cut to 64.
// ---------------------------------------------------------------------------
__global__ __launch_bounds__(256, 4) void binput0(
    const ushort* __restrict__ fbc, const ushort* __restrict__ WT,
    ushort* __restrict__ gout)
{
    __shared__ ushort Xlds[32 * 25 * 8];

    int tid = threadIdx.x;
    int bond0 = blockIdx.x * 32;           // grid = 6875, exact
    int lane = tid & 63, wv = tid >> 6;

    if (tid < 160) {                       // b = tid/5, k8 = tid%5
        int b = tid / 5, k8 = tid - b * 5;
        *(short8*)&Xlds[(b * 25 + k8) * 8] =
            *(const short8*)&fbc[(size_t)bond0 * BOND_IN + tid * 8];
    }
    if (tid < 96) {                        // zero k in [40,64): cells 5..7
        int b = tid / 3, k8 = 5 + (tid - b * 3);
        *(float4*)&Xlds[(b * 25 + k8) * 8] = float4{0.f, 0.f, 0.f, 0.f};
    }
    __syncthreads();

    int n0 = wv * 32;
    int m_lane = lane & 15, quad = lane >> 4;
    f32x4 c00 = {0,0,0,0}, c01 = {0,0,0,0}, c10 = {0,0,0,0}, c11 = {0,0,0,0};

    #pragma unroll
    for (int s = 0; s < 2; s++) {          // K = 64 covers fb (k<40) + zeros
        short8 a0 = *(const short8*)&Xlds[((m_lane)      * 25 + s * 4 + quad) * 8];
        short8 a1 = *(const short8*)&Xlds[((16 + m_lane) * 25 + s * 4 + quad) * 8];
        short8 b0 = *(const short8*)&WT[(size_t)(n0 + m_lane)      * KC + s * 32 + quad * 8];
        short8 b1 = *(const short8*)&WT[(size_t)(n0 + 16 + m_lane) * KC + s * 32 + quad * 8];
        c00 = __builtin_amdgcn_mfma_f32_16x16x32_bf16(a0, b0, c00, 0, 0, 0);
        c01 = __builtin_amdgcn_mfma_f32_16x16x32_bf16(a0, b1, c01, 0, 0, 0);
        c10 = __builtin_amdgcn_mfma_f32_16x16x32_bf16(a1, b0, c10, 0, 0, 0);
        c11 = __builtin_amdgcn_mfma_f32_16x16x32_bf16(a1, b1, c11, 0, 0, 0);
    }

    #pragma unroll
    for (int r = 0; r < 4; r++) {
        int row0 = bond0 + quad * 4 + r;
        int row1 = row0 + 16;
        gout[(size_t)row0 * H + n0 + m_lane]      = f2bf(fmaxf(c00[r], 0.f));
        gout[(size_t)row0 * H + n0 + 16 + m_lane] = f2bf(fmaxf(c01[r], 0.f));
        gout[(size_t)row1 * H + n0 + m_lane]      = f2bf(fmaxf(c10[r], 0.f));
        gout[(size_t)row1 * H + n0 + 16 + m_lane] = f2bf(fmaxf(c11[r], 0.f));
    }
}

// ---------------------------------------------------------------------------
// mp_round (MFMA): graph_out[b] = relu([fb[b]|nei[b]|0] @ [Wi;Wh;0])
// Gather (best measured config, R8): 4 rows per wave-instruction
// (16 lanes x 16 B = one 256 B row); per lane 8 sums = one A-frag cell
// -> single aligned b128 LDS write. ~3.5 TB/s L2-miss delivery = the
// measured ceiling for this random-256B pattern (R5/R8/R9 all converge).
// ---------------------------------------------------------------------------
__global__ __launch_bounds__(256, 4) void mp_round(
    const ushort* __restrict__ msg_in, const ushort* __restrict__ fbc,
    const int* __restrict__ bgraph, const ushort* __restrict__ WT,
    ushort* __restrict__ graph_out)
{
    __shared__ ushort Xlds[32 * 25 * 8];   // 800 cells x 16 B = 12800 B

    int tid = threadIdx.x;
    int bond0 = blockIdx.x * 32;           // grid = 6875, exact
    int lane = tid & 63, wv = tid >> 6;
    int q = lane >> 4, c16 = lane & 15;

    // stage fb tile (pre-converted bf16): 160 x 16 B copies
    if (tid < 160) {
        int b = tid / 5, k8 = tid - b * 5;
        *(short8*)&Xlds[(b * 25 + k8) * 8] =
            *(const short8*)&fbc[(size_t)bond0 * BOND_IN + tid * 8];
    }
    // zero pad k in [168,192): cells 21..23
    if (tid < 96) {
        int b = tid / 3, k8 = 21 + (tid - b * 3);
        *(float4*)&Xlds[(b * 25 + k8) * 8] = float4{0.f, 0.f, 0.f, 0.f};
    }
    // gather nei: wave wv covers rows wv+4t, t = g*4+q; lane sums elements
    // [c16*8, c16*8+8) of its row -> cell 5+c16.
    #pragma unroll
    for (int g = 0; g < 2; g++) {
        int b = wv + 4 * (g * 4 + q);
        const int* bg = bgraph + (size_t)(bond0 + b) * MAX_NB;
        int idx[MAX_NB];
        #pragma unroll
        for (int n = 0; n < MAX_NB; n++) idx[n] = bg[n];
        uint4 v[MAX_NB];
        #pragma unroll
        for (int n = 0; n < MAX_NB; n++)
            v[n] = *(const uint4*)(msg_in + (size_t)idx[n] * H + c16 * 8);
        float s0=0.f,s1=0.f,s2=0.f,s3=0.f,s4=0.f,s5=0.f,s6=0.f,s7=0.f;
        #pragma unroll
        for (int n = 0; n < MAX_NB; n++) {
            s0 += bflo(v[n].x); s1 += bfhi(v[n].x);
            s2 += bflo(v[n].y); s3 += bfhi(v[n].y);
            s4 += bflo(v[n].z); s5 += bfhi(v[n].z);
            s6 += bflo(v[n].w); s7 += bfhi(v[n].w);
        }
        uint4 pk;
        pk.x = ((unsigned int)f2bf(s1) << 16) | (unsigned int)f2bf(s0);
        pk.y = ((unsigned int)f2bf(s3) << 16) | (unsigned int)f2bf(s2);
        pk.z = ((unsigned int)f2bf(s5) << 16) | (unsigned int)f2bf(s4);
        pk.w = ((unsigned int)f2bf(s7) << 16) | (unsigned int)f2bf(s6);
        *(uint4*)&Xlds[(b * 25 + 5 + c16) * 8] = pk;
    }
    __syncthreads();

    int n0 = wv * 32;
    int m_lane = lane & 15, quad = lane >> 4;
    f32x4 c00 = {0,0,0,0}, c01 = {0,0,0,0}, c10 = {0,0,0,0}, c11 = {0,0,0,0};

    #pragma unroll
    for (int s = 0; s < KC / 32; s++) {
        short8 a0 = *(const short8*)&Xlds[((m_lane)      * 25 + s * 4 + quad) * 8];
        short8 a1 = *(const short8*)&Xlds[((16 + m_lane) * 25 + s * 4 + quad) * 8];
        short8 b0 = *(const short8*)&WT[(size_t)(n0 + m_lane)      * KC + s * 32 + quad * 8];
        short8 b1 = *(const short8*)&WT[(size_t)(n0 + 16 + m_lane) * KC + s * 32 + quad * 8];
        c00 = __builtin_amdgcn_mfma_f32_16x16x32_bf16(a0, b0, c00, 0, 0, 0);
        c01 = __builtin_amdgcn_mfma_f32_16x16x32_bf16(a0, b1, c01, 0, 0, 0);
        c10 = __builtin_amdgcn_mfma_f32_16x16x32_bf16(a1, b0, c10, 0, 0, 0);
        c11 = __builtin_amdgcn_mfma_f32_16x16x32_bf16(a1, b1, c11, 0, 0, 0);
    }

    #pragma unroll
    for (int r = 0; r < 4; r++) {
        int row0 = bond0 + quad * 4 + r;
        int row1 = row0 + 16;
        graph_out[(size_t)row0 * H + n0 + m_lane]      = f2bf(fmaxf(c00[r], 0.f));
        graph_out[(size_t)row0 * H + n0 + 16 + m_lane] = f2bf(fmaxf(c01[r], 0.f));
        graph_out[(size_t)row1 * H + n0 + m_lane]      = f2bf(fmaxf(c10[r], 0.f));
        graph_out[(size_t)row1 * H + n0 + 16 + m_lane] = f2bf(fmaxf(c11[r], 0.f));
    }
}

// ---------------------------------------------------------------------------
// atom_mfma: relu([nei|fatoms|0] @ WoT^T + b_o), then per-molecule partial
// sums reduced in LDS (mol_ids sorted -> few segments per 32-atom tile) and
// atomicAdd'ed into out. No hidden buffer.
// ---------------------------------------------------------------------------
__global__ __launch_bounds__(256, 4) void atom_mfma(
    const float* __restrict__ fatoms, const ushort* __restrict__ msg,
    const int* __restrict__ agraph, const ushort* __restrict__ WoT,
    const float* __restrict__ bo, const int* __restrict__ mol_ids,
    float* __restrict__ out)
{
    __shared__ ushort Xlds[32 * 25 * 8];
    __shared__ float htile[32 * H];
    __shared__ int mlds[32];

    int tid = threadIdx.x;
    int a0 = blockIdx.x * 32;              // grid = 3125, exact
    int lane = tid & 63, wv = tid >> 6;
    int q = lane >> 4, c16 = lane & 15;

    // fatoms: k in [128,163)
    for (int i = tid; i < 32 * ATOM_FDIM; i += 256) {
        int b = i / ATOM_FDIM, t = i - b * ATOM_FDIM;
        int k = H + t;
        Xlds[(b * 25 + (k >> 3)) * 8 + (k & 7)] = f2bf(fatoms[(size_t)a0 * ATOM_FDIM + i]);
    }
    // zero k in [163,168)
    if (tid < 160) {
        int b = tid / 5, k = 163 + (tid - b * 5);
        Xlds[(b * 25 + (k >> 3)) * 8 + (k & 7)] = 0;
    }
    // zero cells 21..23 (k in [168,192))
    if (tid < 96) {
        int b = tid / 3, k8 = 21 + (tid - b * 3);
        *(float4*)&Xlds[(b * 25 + k8) * 8] = float4{0.f, 0.f, 0.f, 0.f};
    }
    if (tid < 32) mlds[tid] = mol_ids[a0 + tid];
    // gather nei: k in [0,128) -> cell c16
    #pragma unroll
    for (int g = 0; g < 2; g++) {
        int b = wv + 4 * (g * 4 + q);
        const int* ag = agraph + (size_t)(a0 + b) * MAX_NB;
        int idx[MAX_NB];
        #pragma unroll
        for (int n = 0; n < MAX_NB; n++) idx[n] = ag[n];
        uint4 v[MAX_NB];
        #pragma unroll
        for (int n = 0; n < MAX_NB; n++)
            v[n] = *(const uint4*)(msg + (size_t)idx[n] * H + c16 * 8);
        float s0=0.f,s1=0.f,s2=0.f,s3=0.f,s4=0.f,s5=0.f,s6=0.f,s7=0.f;
        #pragma unroll
        for (int n = 0; n < MAX_NB; n++) {
            s0 += bflo(v[n].x); s1 += bfhi(v[n].x);
            s2 += bflo(v[n].y); s3 += bfhi(v[n].y);
            s4 += bflo(v[n].z); s5 += bfhi(v[n].z);
            s6 += bflo(v[n].w); s7 += bfhi(v[n].w);
        }
        uint4 pk;
        pk.x = ((unsigned int)f2bf(s1) << 16) | (unsigned int)f2bf(s0);
        pk.y = ((unsigned int)f2bf(s3) << 16) | (unsigned int)f2bf(s2);
        pk.z = ((unsigned int)f2bf(s5) << 16) | (unsigned int)f2bf(s4);
        pk.w = ((unsigned int)f2bf(s7) << 16) | (unsigned int)f2bf(s6);
        *(uint4*)&Xlds[(b * 25 + c16) * 8] = pk;
    }
    __syncthreads();

    int n0 = wv * 32;
    int m_lane = lane & 15, quad = lane >> 4;
    float bias0 = bo[n0 + m_lane], bias1 = bo[n0 + 16 + m_lane];
    f32x4 c00 = {bias0, bias0, bias0, bias0};
    f32x4 c01 = {bias1, bias1, bias1, bias1};
    f32x4 c10 = {bias0, bias0, bias0, bias0};
    f32x4 c11 = {bias1, bias1, bias1, bias1};

    #pragma unroll
    for (int s = 0; s < KC / 32; s++) {
        short8 a0f = *(const short8*)&Xlds[((m_lane)      * 25 + s * 4 + quad) * 8];
        short8 a1f = *(const short8*)&Xlds[((16 + m_lane) * 25 + s * 4 + quad) * 8];
        short8 b0f = *(const short8*)&WoT[(size_t)(n0 + m_lane)      * KC + s * 32 + quad * 8];
        short8 b1f = *(const short8*)&WoT[(size_t)(n0 + 16 + m_lane) * KC + s * 32 + quad * 8];
        c00 = __builtin_amdgcn_mfma_f32_16x16x32_bf16(a0f, b0f, c00, 0, 0, 0);
        c01 = __builtin_amdgcn_mfma_f32_16x16x32_bf16(a0f, b1f, c01, 0, 0, 0);
        c10 = __builtin_amdgcn_mfma_f32_16x16x32_bf16(a1f, b0f, c10, 0, 0, 0);
        c11 = __builtin_amdgcn_mfma_f32_16x16x32_bf16(a1f, b1f, c11, 0, 0, 0);
    }

    #pragma unroll
    for (int r = 0; r < 4; r++) {
        int r0 = quad * 4 + r, r1 = r0 + 16;
        htile[r0 * H + n0 + m_lane]      = fmaxf(c00[r], 0.f);
        htile[r0 * H + n0 + 16 + m_lane] = fmaxf(c01[r], 0.f);
        htile[r1 * H + n0 + m_lane]      = fmaxf(c10[r], 0.f);
        htile[r1 * H + n0 + 16 + m_lane] = fmaxf(c11[r], 0.f);
    }
    __syncthreads();

    // segmented reduce over the 32-atom tile, one atomicAdd per (segment,col)
    if (tid < H) {
        int j = tid;
        float acc = 0.f;
        int cur = mlds[0];
        for (int r = 0; r < 32; r++) {
            int m = mlds[r];
            if (m != cur) {
                atomicAdd(&out[(size_t)cur * H + j], acc);
                acc = 0.f; cur = m;
            }
            acc += htile[r * H + j];
        }
        atomicAdd(&out[(size_t)cur * H + j], acc);
    }
}

// ---------------------------------------------------------------------------
// pool_div: out[m] /= count(m)  (counts via binary search on sorted mol_ids)
// ---------------------------------------------------------------------------
__global__ __launch_bounds__(128) void pool_div(
    const int* __restrict__ mol_ids, float* __restrict__ out, int n_atoms)
{
    int m = blockIdx.x;
    int j = threadIdx.x;

    int lo = 0, hi = n_atoms;
    while (lo < hi) { int mid = (lo + hi) >> 1; if (mol_ids[mid] < m) lo = mid + 1; else hi = mid; }
    int start = lo;
    hi = n_atoms;
    while (lo < hi) { int mid = (lo + hi) >> 1; if (mol_ids[mid] < m + 1) lo = mid + 1; else hi = mid; }
    int end = lo;

    out[(size_t)m * H + j] /= fmaxf((float)(end - start), 1.f);
}

// ---------------------------------------------------------------------------
extern "C" void kernel_launch(void* const* d_in, const int* in_sizes, int n_in,
                              void* d_out, int out_size, void* d_ws, size_t ws_size,
                              hipStream_t stream)
{
    const float* fatoms  = (const float*)d_in[0];
    const float* fbonds  = (const float*)d_in[1];
    const float* tree    = (const float*)d_in[2];
    const int*   agraph  = (const int*)d_in[3];
    const int*   bgraph  = (const int*)d_in[4];
    const int*   mol_ids = (const int*)d_in[5];
    const float* W_i = (const float*)d_in[7];
    const float* W_h = (const float*)d_in[8];
    const float* W_o = (const float*)d_in[9];
    const float* b_o = (const float*)d_in[10];
    float* out = (float*)d_out;

    // ws: msgA | msgB (bf16, 61.44 MB each) | WT | WoT (48 KB each) | fbc (17.6 MB)
    ushort* msgA = (ushort*)d_ws;
    ushort* msgB = msgA + (size_t)N_MSG * H;
    ushort* WT   = msgB + (size_t)N_MSG * H;
    ushort* WoT  = WT + (size_t)H * KC;
    ushort* fbc  = WoT + (size_t)H * KC;

    int prep_total = PT3 + out_size;
    prep<<<(prep_total + 255) / 256, 256, 0, stream>>>(
        tree, fbonds, W_i, W_h, W_o, msgA, msgB, fbc, WT, WoT, out, out_size);

    binput0<<<N_BONDS / 32, 256, 0, stream>>>(fbc, WT, msgA + (size_t)N_MESS * H);

    const ushort* min_ = msgA; ushort* mout = msgB;
    for (int r = 0; r < DEPTH - 1; r++) {
        mp_round<<<N_BONDS / 32, 256, 0, stream>>>(min_, fbc, bgraph, WT,
                                                   mout + (size_t)N_MESS * H);
        const ushort* t = min_; min_ = mout; mout = (ushort*)t;
    }
    // after 5 rounds the final message table is msgB (== min_)

    atom_mfma<<<N_ATOMS / 32, 256, 0, stream>>>(fatoms, min_, agraph, WoT, b_o,
                                                mol_ids, out);

    int n_mols = out_size / H;
    pool_div<<<n_mols, 128, 0, stream>>>(mol_ids, out, N_ATOMS);
}